// Round 1
// baseline (63.154 us; speedup 1.0000x reference)
//
#include <hip/hip_runtime.h>

// Problem constants (from reference)
#define NT     101            // (SLEN - PTILE)/STEP + 1 = (208-8)/2+1
#define PTILES (NT * NT)      // 10201 tiles
#define BATCH  16
#define NSRC   100
#define NTILES (BATCH * PTILES)   // 163216
#define TOTF   (17 * NTILES)      // 2,774,672 floats = 11.1 MB total output
#define F4TOT  (TOTF / 4)         // 693,668 float4s (divides exactly)

// ---------------------------------------------------------------------------
// Pass 1: stream zeros over the entire output. ~99% of output words are
// exactly 0 in the reference (off-slots are zeroed by is_on masking + relu),
// so the bulk write is a pure memset-shaped job: no LDS, no barriers, no
// branches -> near-peak HBM write BW.
// ---------------------------------------------------------------------------
__global__ __launch_bounds__(256)
void ImageEncoder_zero_fill(float4* __restrict__ out)
{
    const int stride = gridDim.x * blockDim.x;
    for (int i = blockIdx.x * blockDim.x + threadIdx.x; i < F4TOT; i += stride)
        out[i] = make_float4(0.f, 0.f, 0.f, 0.f);
}

// ---------------------------------------------------------------------------
// Pass 2: scatter the ~95 on-sources per batch into their tiles.
// One block per batch, one thread per source. Each source is "on" in at most
// one tile; argsort(-is_on) is stable, so slot k of a tile is the k-th
// on-source in s order. rank = #{j < s : same tile}, computed from an LDS
// table of all 100 candidate tile ids. Only rank<2 sources write (~8 floats
// each); out_n written by rank==0 with min(cnt,2).
// On/off decision is bit-identical to the previous passing kernel
// (floor-derived r,c validated by the exact reference open-interval compares).
// ---------------------------------------------------------------------------
__global__ __launch_bounds__(128)
void ImageEncoder_sparse_fill(const float* __restrict__ locs,
                              const float* __restrict__ fluxes,
                              float* __restrict__ out)
{
    __shared__ int   s_tc[128];
    __shared__ float s_y[128];
    __shared__ float s_x[128];

    const int s = threadIdx.x;
    const int b = blockIdx.x;

    int   tc = -1;
    float yp = 0.f, xp = 0.f;
    if (s < NSRC) {
        const float2 yx = ((const float2*)(locs + b * (NSRC * 2)))[s];
        yp = yx.x * 207.0f;
        xp = yx.y * 207.0f;
        int r = (int)floorf((yp - 2.5f) * 0.5f);
        int c = (int)floorf((xp - 2.5f) * 0.5f);
        bool ok = (r >= 0) & (r < NT) & (c >= 0) & (c < NT);
        if (ok) {
            // exact reference comparisons (bit-identical decision)
            const float ly = (float)(2 * r) + 2.5f;
            const float lx = (float)(2 * c) + 2.5f;
            ok = (yp > ly) & (yp < ly + 2.0f) & (xp > lx) & (xp < lx + 2.0f);
        }
        if (ok) tc = r * NT + c;
    }
    s_tc[s] = tc;
    s_y[s]  = yp;
    s_x[s]  = xp;
    __syncthreads();

    if (tc < 0) return;

    // stable rank among on-sources sharing this tile, and total count
    int rank = 0, cnt = 0;
    #pragma unroll 4
    for (int j = 0; j < NSRC; ++j) {
        const bool same = (s_tc[j] == tc);
        cnt  += same ? 1 : 0;
        rank += (same & (j < s)) ? 1 : 0;
    }

    // Output layout (flat f32, reference return order):
    //   [0,          NTILES)    n_sources
    //   [NTILES,     NTILES*5)  tile_locs   (NTILES,2,2)
    //   [NTILES*5,   NTILES*15) tile_fluxes (NTILES,2,5)
    //   [NTILES*15,  NTILES*17) tile_is_on  (NTILES,2)
    float* out_n = out;
    float* out_l = out + NTILES;
    float* out_f = out + (size_t)NTILES * 5;
    float* out_o = out + (size_t)NTILES * 15;

    const int t = b * PTILES + tc;

    if (rank == 0)
        out_n[t] = fminf((float)cnt, 2.0f);

    if (rank < 2) {
        const int   row = tc / NT;
        const int   col = tc - row * NT;
        const float ly  = (float)(2 * row) + 2.5f;
        const float lx  = (float)(2 * col) + 2.5f;

        // (yp-ly)*0.5f == (locs_pix-left)/scale, scale=2; value in (0,1) so
        // reference relu is a no-op. 8-byte aligned (t*4 + 2*rank is even).
        *(float2*)(out_l + (size_t)t * 4 + 2 * rank) =
            make_float2((yp - ly) * 0.5f, (xp - lx) * 0.5f);

        out_o[(size_t)t * 2 + rank] = 1.0f;

        const float* fb = fluxes + (size_t)(b * NSRC + s) * 5;
        float*       fo = out_f + (size_t)t * 10 + 5 * rank;
        #pragma unroll
        for (int j = 0; j < 5; ++j) fo[j] = fb[j];
    }
}

extern "C" void kernel_launch(void* const* d_in, const int* in_sizes, int n_in,
                              void* d_out, int out_size, void* d_ws, size_t ws_size,
                              hipStream_t stream) {
    const float* locs   = (const float*)d_in[0];   // (16, 100, 2) f32
    const float* fluxes = (const float*)d_in[1];   // (16, 100, 5) f32
    float* out = (float*)d_out;                    // 17 * NTILES f32

    // Pass 1: streaming zero of the whole output (11.1 MB).
    // 678 blocks * 256 threads, grid-stride (~4 float4 stores/thread).
    ImageEncoder_zero_fill<<<dim3(678), 256, 0, stream>>>((float4*)out);

    // Pass 2: scatter the ~1520 nonzero tile entries (stream-ordered after
    // the zero pass, so no write races).
    ImageEncoder_sparse_fill<<<dim3(BATCH), 128, 0, stream>>>(locs, fluxes, out);
}

// Round 2
// 60.356 us; speedup vs baseline: 1.0464x; 1.0464x over previous
//
#include <hip/hip_runtime.h>

// Problem constants (from reference)
#define NT     101            // (SLEN - PTILE)/STEP + 1 = (208-8)/2+1
#define PTILES (NT * NT)      // 10201 tiles
#define BATCH  16
#define NSRC   100
#define NTILES (BATCH * PTILES)   // 163216
#define PBLK   256            // tiles per block
#define NBLKX  ((PTILES + PBLK - 1) / PBLK)   // 40

// Single dispatch (launch overhead ~10us/dispatch dominates: two-kernel split
// regressed 59->63us). Block = (batch, 256-tile strip), one thread per tile.
// Stage the batch's 100 sources, ballot-compact (s-order preserved) the ~2.4
// whose candidate tile lies in this strip, per-tile scan those, then write
// ALL output sections directly from registers:
//   n:    stride-1 scalar/thread   -> dense 256B/wave
//   locs: stride-4 float4/thread   -> dense 4KB/wave, 16B aligned
//   is_on:stride-2 float2/thread   -> dense 2KB/wave
//   flux: 5x stride-10 float2/thread -> union fully contiguous, L2 combines
// vs R0: no 10KB flux LDS staging, no second __syncthreads, no copy loop.

__global__ __launch_bounds__(256)
void ImageEncoder_41944650613092_kernel(const float* __restrict__ locs,
                                        const float* __restrict__ fluxes,
                                        float* __restrict__ out)
{
    __shared__ int   s_cnt[2];
    __shared__ int   s_tc[NSRC];     // compacted candidate tile ids (s-order)
    __shared__ int   s_id[NSRC];     // compacted source indices
    __shared__ float s_y[NSRC];
    __shared__ float s_x[NSRC];

    const int tid   = threadIdx.x;
    const int b     = blockIdx.y;
    const int pbase = blockIdx.x * PBLK;
    const int p     = pbase + tid;

    // ---- stage + filter ----
    bool  m  = false;
    int   tc = -1;
    float yp = 0.f, xp = 0.f;
    if (tid < NSRC) {
        const float2 yx = ((const float2*)(locs + b * (NSRC * 2)))[tid];
        yp = yx.x * 207.0f;
        xp = yx.y * 207.0f;
        int r = (int)floorf((yp - 2.5f) * 0.5f);
        int c = (int)floorf((xp - 2.5f) * 0.5f);
        bool ok = (r >= 0) & (r < NT) & (c >= 0) & (c < NT);
        if (ok) {
            // exact reference comparisons (bit-identical decision)
            const float ly = (float)(2 * r) + 2.5f;
            const float lx = (float)(2 * c) + 2.5f;
            ok = (yp > ly) & (yp < ly + 2.0f) & (xp > lx) & (xp < lx + 2.0f);
        }
        tc = r * NT + c;
        m  = ok & (tc >= pbase) & (tc < pbase + PBLK);
    }

    // ---- order-preserving compaction (waves 0 and 1 only hold sources) ----
    int pos = 0;
    if (tid < 128) {
        const unsigned long long ball = __ballot(m);
        const int lane = tid & 63;
        const int wave = tid >> 6;
        if (lane == 0) s_cnt[wave] = __popcll(ball);
        pos = __popcll(ball & ((1ull << lane) - 1ull));
    }
    __syncthreads();
    if (m) {
        const int idx = ((tid >> 6) ? s_cnt[0] : 0) + pos;
        s_tc[idx] = tc;
        s_id[idx] = tid;
        s_y[idx]  = yp;
        s_x[idx]  = xp;
    }
    const int total = s_cnt[0] + s_cnt[1];
    __syncthreads();

    // ---- scan the few candidates; first two matches in s order ----
    int cnt = 0, i0 = -1, i1 = -1;
    for (int i = 0; i < total; ++i) {   // block-uniform bound, ~2-3 typical
        if (s_tc[i] == p) {
            if (cnt == 0)      i0 = i;
            else if (cnt == 1) i1 = i;
            ++cnt;
        }
    }

    if (p >= PTILES) return;            // last strip tail (217 valid tiles)

    // ---- build per-tile outputs in registers ----
    float l4[4]   = {0.f, 0.f, 0.f, 0.f};
    float f10[10] = {0.f, 0.f, 0.f, 0.f, 0.f, 0.f, 0.f, 0.f, 0.f, 0.f};
    float o2[2]   = {0.f, 0.f};

    const int row = p / NT;
    const int col = p - row * NT;
    const float ly = (float)(2 * row) + 2.5f;
    const float lx = (float)(2 * col) + 2.5f;

    #pragma unroll
    for (int k = 0; k < 2; ++k) {
        const int i = (k == 0) ? i0 : i1;
        if (i >= 0) {
            l4[2 * k]     = (s_y[i] - ly) * 0.5f;   // /scale, scale = 2
            l4[2 * k + 1] = (s_x[i] - lx) * 0.5f;
            const float* fb = fluxes + (size_t)(b * NSRC + s_id[i]) * 5;
            #pragma unroll
            for (int j = 0; j < 5; ++j) f10[5 * k + j] = fb[j];
            o2[k] = 1.0f;
        }
    }

    // Output layout (flat f32, reference return order):
    //   [0,          NTILES)    n_sources
    //   [NTILES,     NTILES*5)  tile_locs   (NTILES,2,2)
    //   [NTILES*5,   NTILES*15) tile_fluxes (NTILES,2,5)
    //   [NTILES*15,  NTILES*17) tile_is_on  (NTILES,2)
    float* out_n = out;
    float* out_l = out + NTILES;
    float* out_f = out + (size_t)NTILES * 5;
    float* out_o = out + (size_t)NTILES * 15;

    const int t = b * PTILES + p;

    out_n[t] = fminf((float)cnt, 2.0f);
    *(float4*)(out_l + (size_t)t * 4) = make_float4(l4[0], l4[1], l4[2], l4[3]);
    *(float2*)(out_o + (size_t)t * 2) = make_float2(o2[0], o2[1]);

    float2* fo = (float2*)(out_f + (size_t)t * 10);   // t*10 even -> 8B aligned
    fo[0] = make_float2(f10[0], f10[1]);
    fo[1] = make_float2(f10[2], f10[3]);
    fo[2] = make_float2(f10[4], f10[5]);
    fo[3] = make_float2(f10[6], f10[7]);
    fo[4] = make_float2(f10[8], f10[9]);
}

extern "C" void kernel_launch(void* const* d_in, const int* in_sizes, int n_in,
                              void* d_out, int out_size, void* d_ws, size_t ws_size,
                              hipStream_t stream) {
    const float* locs   = (const float*)d_in[0];   // (16, 100, 2) f32
    const float* fluxes = (const float*)d_in[1];   // (16, 100, 5) f32
    float* out = (float*)d_out;                    // 17 * NTILES f32

    dim3 grid(NBLKX, BATCH);   // 40 x 16 = 640 blocks, one dispatch
    ImageEncoder_41944650613092_kernel<<<grid, 256, 0, stream>>>(locs, fluxes, out);
}